// Round 19
// baseline (50.218 us; speedup 1.0000x reference)
//
#include <hip/hip_runtime.h>

// Actor MLP, B=262144 rows, fp32 in/out. All three GEMM stages on MFMA.
// R19: phase 1 (14x 9->16->4 MLP) as virtual-row GEMM (vr = g*64+r, M=896):
//   layer1: D[h][vr] = W1T(A) @ x(B), f16 16x16x32, K-slots via custom
//   bijection kappa(p,j) = p*4+j (j<4) else 16+p*4+j-4, zeros above K=16.
//   C/D of layer1 (col=vr=lane&15, rows=h=(lane>>4)*4+i) IS layer2's
//   B-frag slot layout -> relu+cvt_pkrtz chains in registers, no transpose.
//   layer2: D[o][vr] = W2T(A) @ h(B); lanes p==0 hold s-quads -> b64 write.
// Phases 2+3 (57->128->30) unchanged from R18 (bf16 MFMA, B hi+lo split,
// C/D-native z tiles + ds_read_b64_tr_b16). 2 barriers. (256,4).

typedef float f4v  __attribute__((ext_vector_type(4)));
typedef short s8v  __attribute__((ext_vector_type(8)));
typedef _Float16 h8v __attribute__((ext_vector_type(8)));
typedef unsigned u2v __attribute__((ext_vector_type(2)));
typedef unsigned u4v __attribute__((ext_vector_type(4)));

constexpr int NG = 14, GI = 9, FH = 128, AD = 15;

__device__ __forceinline__ unsigned short f2bf(float f) {
    unsigned u = __builtin_bit_cast(unsigned, f);
    return (unsigned short)((u + 0x7fffu + ((u >> 16) & 1u)) >> 16);
}
__device__ __forceinline__ float bf2f(unsigned short h) {
    return __builtin_bit_cast(float, (unsigned)h << 16);
}
__device__ __forceinline__ f4v load4u(const float* p) {
    f4v v; __builtin_memcpy(&v, p, 16); return v;
}
__device__ __forceinline__ unsigned pkh(float a, float b) {
    return __builtin_bit_cast(unsigned, __builtin_amdgcn_cvt_pkrtz(a, b));
}
__device__ __forceinline__ unsigned pkbf(float a, float b) {
    unsigned r;
    asm("v_cvt_pk_bf16_f32 %0, %1, %2" : "=v"(r) : "v"(a), "v"(b));
    return r;
}

// pk layout (shorts): W3h[0,8192) W3l[8192,16384) W4h[16384,20480)
// W4l[20480,24576) W1T[24576,25088) W2T[25088,25600)
__global__ void pack_kernel(const float* __restrict__ W3,
                            const float* __restrict__ W4,
                            const float* __restrict__ W1,
                            const float* __restrict__ W2,
                            unsigned short* __restrict__ pk) {
    unsigned short* W3h = pk;
    unsigned short* W3l = pk + 8192;
    unsigned short* W4h = pk + 16384;
    unsigned short* W4l = pk + 20480;
    int t = blockIdx.x * 256 + threadIdx.x;
    if (t < 8192) {
        int j = t & 7, l = (t >> 3) & 63, nt = (t >> 9) & 7, kt = t >> 12;
        int k = kt * 32 + (l >> 4) * 8 + j, n = nt * 16 + (l & 15);
        float v = (k < 57) ? W3[k * FH + n] : 0.f;
        unsigned short h = f2bf(v);
        W3h[t] = h;
        W3l[t] = f2bf(v - bf2f(h));
    }
    if (t < 4096) {
        int j = t & 7, l = (t >> 3) & 63, nt = (t >> 9) & 1, kt = t >> 10;
        int k = kt * 32 + (l >> 4) * 8 + j, n = nt * 16 + (l & 15);
        float v = (n < 30) ? W4[k * 30 + n] : 0.f;
        unsigned short h = f2bf(v);
        W4h[t] = h;
        W4l[t] = f2bf(v - bf2f(h));
    }
    if (t < 512) {   // W1T + W2T A-frags, kappa(p,j)
        int l = t >> 3, j = t & 7;
        int p = l >> 4, m = l & 15;
        int k = (j < 4) ? (p * 4 + j) : (16 + p * 4 + (j - 4));
        float v1 = (k < GI) ? W1[k * 16 + m] : 0.f;          // W1 [9][16]
        float v2 = (k < 16 && m < 4) ? W2[k * 4 + m] : 0.f;  // W2 [16][4]
        _Float16 h1 = (_Float16)v1, h2 = (_Float16)v2;
        pk[24576 + t] = __builtin_bit_cast(unsigned short, h1);
        pk[25088 + t] = __builtin_bit_cast(unsigned short, h2);
    }
}

__global__ __launch_bounds__(256, 4) void actor_fused(
    const float* __restrict__ x,     // [B,126]
    const float* __restrict__ sale,  // [B,1]
    const float* __restrict__ b1,    // [16]
    const float* __restrict__ b2,    // [4]
    const float* __restrict__ b3,    // [128]
    const float* __restrict__ b4,    // [30]
    const unsigned short* __restrict__ pk,
    float* __restrict__ om, float* __restrict__ os)
{
    // xz 16 KB. Life 1: x fp16 [64][126]. Life 2 (after bar 1): z bf16 tiled.
    // sh 8 KB: s bf16 [64][64] row-swizzled.
    __shared__ unsigned short xz[8192];
    __shared__ unsigned short sh[4096];

    const int tid  = threadIdx.x;
    const int wv   = __builtin_amdgcn_readfirstlane(tid >> 6);  // wave 0..3
    const int lane = tid & 63;
    const int row0 = blockIdx.x * 64;
    const int p    = lane >> 4;
    const int col  = lane & 15;

    // ---- wave-private x stage: rows [16wv, 16wv+16) -> fp16 LDS ----
    {
        const float* xs = x + (size_t)(row0 + 16 * wv) * (NG * GI);
        unsigned* xw = (unsigned*)(xz + 16 * wv * 126);
        #pragma unroll
        for (int j = 0; j < 8; ++j) {
            int ci = j * 64 + lane;
            if (j < 7 || ci < 504) {
                f4v v = load4u(xs + 4 * ci);
                *(u2v*)(xw + 2 * ci) = (u2v){pkh(v[0], v[1]), pkh(v[2], v[3])};
            }
        }
    }
    // sale (k=56) + zero K-pad (k=57..63) for this wave's 16 rows
    if (lane < 16) {
        int r = 16 * wv + lane;
        float sv = sale[row0 + r];
        int byt = (r * 128 + 112) ^ ((r & 7) << 4);
        *(unsigned short*)((char*)sh + byt) = f2bf(sv);
        #pragma unroll
        for (int kk = 57; kk < 64; ++kk) {
            int bb = (r * 128 + kk * 2) ^ ((r & 7) << 4);
            *(unsigned short*)((char*)sh + bb) = 0;
        }
    }

    // ---- phase 1: virtual-row MFMA; wave wv owns rows 16wv..16wv+15 ----
    const int r1 = 16 * wv + col;
    const h8v w1t = __builtin_bit_cast(h8v, *(const s8v*)(pk + 24576 + lane * 8));
    const h8v w2t = __builtin_bit_cast(h8v, *(const s8v*)(pk + 25088 + lane * 8));
    const f4v b1f = load4u(b1 + p * 4);     // C-init rows h = p*4..p*4+3
    const f4v b2f = load4u(b2);             // valid for p==0 lanes
    const unsigned m0 = (p < 2) ? 0xFFFFFFFFu : (p == 2 ? 0x0000FFFFu : 0u);
    const unsigned m1 = (p < 2) ? 0xFFFFFFFFu : 0u;
    const unsigned short* xbase = xz + (r1 * 126 + p * 4);
    const int sbase = r1 * 128;
    const int ssw   = (r1 & 7) << 4;

    #pragma unroll
    for (int g = 0; g < NG; ++g) {
        unsigned l0 = xbase[g * 9 + 0], l1 = xbase[g * 9 + 1];
        unsigned l2 = xbase[g * 9 + 2], l3 = xbase[g * 9 + 3];
        unsigned u0 = (l0 | (l1 << 16)) & m0;
        unsigned u1 = (l2 | (l3 << 16)) & m1;
        h8v xb = __builtin_bit_cast(h8v, (u4v){u0, u1, 0u, 0u});
        f4v ha = __builtin_amdgcn_mfma_f32_16x16x32_f16(w1t, xb, b1f, 0, 0, 0);
        float h0 = fmaxf(ha[0], 0.f), h1 = fmaxf(ha[1], 0.f);
        float h2 = fmaxf(ha[2], 0.f), h3 = fmaxf(ha[3], 0.f);
        h8v hb = __builtin_bit_cast(h8v, (u4v){pkh(h0, h1), pkh(h2, h3), 0u, 0u});
        f4v sa = __builtin_amdgcn_mfma_f32_16x16x32_f16(w2t, hb, b2f, 0, 0, 0);
        float s0 = fmaxf(sa[0], 0.f), s1 = fmaxf(sa[1], 0.f);
        float s2 = fmaxf(sa[2], 0.f), s3 = fmaxf(sa[3], 0.f);
        unsigned q0 = pkbf(s0, s1), q1 = pkbf(s2, s3);
        if (p == 0) {
            int byt = (sbase + g * 8) ^ ssw;
            *(u2v*)((char*)sh + byt) = (u2v){q0, q1};
        }
    }

    __syncthreads();   // bar 1: all s ready; x region now dead

    // ---------------- phase 2: z[64,128] = s[64,64] @ W3  (MFMA) ----------
    const s8v* W3hv = (const s8v*)pk;
    const s8v* W3lv = (const s8v*)(pk + 8192);
    s8v bh[2][2], bl[2][2];
    #pragma unroll
    for (int kt = 0; kt < 2; ++kt)
        #pragma unroll
        for (int ntl = 0; ntl < 2; ++ntl) {
            int nt = 2 * wv + ntl;
            bh[kt][ntl] = W3hv[(kt * 8 + nt) * 64 + lane];
            bl[kt][ntl] = W3lv[(kt * 8 + nt) * 64 + lane];
        }
    f4v acc[4][2];
    #pragma unroll
    for (int ntl = 0; ntl < 2; ++ntl) {
        float bv = b3[32 * wv + ntl * 16 + col];
        #pragma unroll
        for (int mt = 0; mt < 4; ++mt) acc[mt][ntl] = (f4v){bv, bv, bv, bv};
    }
    #pragma unroll
    for (int kt = 0; kt < 2; ++kt) {
        s8v ah[4];
        #pragma unroll
        for (int mt = 0; mt < 4; ++mt) {
            int rr = mt * 16 + col;
            int byt = (rr * 128 + kt * 64 + p * 16) ^ ((rr & 7) << 4);
            ah[mt] = *(const s8v*)((char*)sh + byt);
        }
        #pragma unroll
        for (int mt = 0; mt < 4; ++mt)
            #pragma unroll
            for (int ntl = 0; ntl < 2; ++ntl) {
                acc[mt][ntl] = __builtin_amdgcn_mfma_f32_16x16x32_bf16(ah[mt], bh[kt][ntl], acc[mt][ntl], 0, 0, 0);
                acc[mt][ntl] = __builtin_amdgcn_mfma_f32_16x16x32_bf16(ah[mt], bl[kt][ntl], acc[mt][ntl], 0, 0, 0);
            }
    }
    // stage relu(z) into C/D-native tiled layout (2 cvt_pk + b64 per frag)
    #pragma unroll
    for (int mt = 0; mt < 4; ++mt)
        #pragma unroll
        for (int ntl = 0; ntl < 2; ++ntl) {
            int kk  = ntl * 16 + col;               // K & 31 (chunk = wv)
            int tau = (kk & 4) ? 4 + (kk >> 3) : (kk >> 3);
            int eidx = mt * 2048 + wv * 512 + tau * 64 + (kk & 3) * 16 + (p << 2);
            float v0 = fmaxf(acc[mt][ntl][0], 0.f);
            float v1 = fmaxf(acc[mt][ntl][1], 0.f);
            float v2 = fmaxf(acc[mt][ntl][2], 0.f);
            float v3 = fmaxf(acc[mt][ntl][3], 0.f);
            *(u2v*)(xz + eidx) = (u2v){pkbf(v0, v1), pkbf(v2, v3)};
        }

    __syncthreads();   // bar 2: z ready

    // ---- phase 3: out[64,30] = z @ W4; A-frags via ds_read_b64_tr_b16 ----
    const s8v* W4hv = (const s8v*)(pk + 16384);
    const s8v* W4lv = (const s8v*)(pk + 20480);
    const int mq   = __builtin_amdgcn_readfirstlane(wv >> 1);  // row-half
    const int nq   = __builtin_amdgcn_readfirstlane(wv & 1);   // col-half
    const int ocol = nq * 16 + col;
    const float b4i = (ocol < 30) ? b4[ocol] : 0.f;

    s8v wh[4], wl[4];
    #pragma unroll
    for (int kt = 0; kt < 4; ++kt) {
        wh[kt] = W4hv[(kt * 2 + nq) * 64 + lane];
        wl[kt] = W4lv[(kt * 2 + nq) * 64 + lane];
    }
    unsigned base = (unsigned)(size_t)&xz[0] + (unsigned)(2 * mq) * 4096u
                  + (unsigned)(lane * 8);
    u2v f0[4][2], f1[4][2];
    #pragma unroll
    for (int c = 0; c < 4; ++c) {
        unsigned a0 = base + c * 1024;
        unsigned a1 = a0 + 4096;
        asm volatile("ds_read_b64_tr_b16 %0, %1" : "=v"(f0[c][0]) : "v"(a0));
        asm volatile("ds_read_b64_tr_b16 %0, %1 offset:512" : "=v"(f0[c][1]) : "v"(a0));
        asm volatile("ds_read_b64_tr_b16 %0, %1" : "=v"(f1[c][0]) : "v"(a1));
        asm volatile("ds_read_b64_tr_b16 %0, %1 offset:512" : "=v"(f1[c][1]) : "v"(a1));
    }
    asm volatile("s_waitcnt lgkmcnt(0)" ::: "memory");
    __builtin_amdgcn_sched_barrier(0);

    f4v oa0 = (f4v){b4i, b4i, b4i, b4i};
    f4v oa1 = oa0;
    #pragma unroll
    for (int kt = 0; kt < 4; ++kt) {
        s8v z0 = __builtin_bit_cast(s8v,
            (u4v){f0[kt][0][0], f0[kt][0][1], f0[kt][1][0], f0[kt][1][1]});
        s8v z1 = __builtin_bit_cast(s8v,
            (u4v){f1[kt][0][0], f1[kt][0][1], f1[kt][1][0], f1[kt][1][1]});
        oa0 = __builtin_amdgcn_mfma_f32_16x16x32_bf16(z0, wh[kt], oa0, 0, 0, 0);
        oa0 = __builtin_amdgcn_mfma_f32_16x16x32_bf16(z0, wl[kt], oa0, 0, 0, 0);
        oa1 = __builtin_amdgcn_mfma_f32_16x16x32_bf16(z1, wh[kt], oa1, 0, 0, 0);
        oa1 = __builtin_amdgcn_mfma_f32_16x16x32_bf16(z1, wl[kt], oa1, 0, 0, 0);
    }
    #pragma unroll
    for (int mi = 0; mi < 2; ++mi) {
        f4v oa = mi ? oa1 : oa0;
        #pragma unroll
        for (int i = 0; i < 4; ++i) {
            int grow = row0 + mq * 32 + mi * 16 + p * 4 + i;
            float v = oa[i];
            if (ocol < AD) {
                float tc = fminf(fmaxf(v, -20.f), 20.f);
                float e = __expf(2.f * tc);
                om[(size_t)grow * AD + ocol] = (e - 1.f) / (e + 1.f);
            } else if (ocol < 2 * AD) {
                os[(size_t)grow * AD + (ocol - AD)] = __expf(v);
            }
        }
    }
}

extern "C" void kernel_launch(void* const* d_in, const int* in_sizes, int n_in,
                              void* d_out, int out_size, void* d_ws, size_t ws_size,
                              hipStream_t stream) {
    const float* x    = (const float*)d_in[0];
    const float* sale = (const float*)d_in[1];
    const float* W1   = (const float*)d_in[2];
    const float* b1   = (const float*)d_in[3];
    const float* W2   = (const float*)d_in[4];
    const float* b2   = (const float*)d_in[5];
    const float* W3   = (const float*)d_in[6];
    const float* b3   = (const float*)d_in[7];
    const float* W4   = (const float*)d_in[8];
    const float* b4   = (const float*)d_in[9];

    int B = in_sizes[1];                       // sale_predictions is [B,1]
    float* om = (float*)d_out;                 // action_mean flat [B*15]
    float* os = om + (size_t)B * AD;           // action_std  flat [B*15]
    unsigned short* pk = (unsigned short*)d_ws;  // 25600 shorts = 51.2 KB

    pack_kernel<<<32, 256, 0, stream>>>(W3, W4, W1, W2, pk);
    actor_fused<<<B / 64, 256, 0, stream>>>(x, sale, b1, b2, b3, b4,
                                            pk, om, os);
}

// Round 20
// 49.369 us; speedup vs baseline: 1.0172x; 1.0172x over previous
//
#include <hip/hip_runtime.h>

// Actor MLP, B=262144 rows, fp32 in/out. All three GEMM stages on MFMA.
// R20 = R19 + x stored in LDS as three p-slices [p][row 64][g 14][4 shorts]
// (slice p holds k=4p..4p+3 of each group; p2 zero-padded; slices offset
// +32B for bank spread): phase-1 per-group read = ONE aligned ds_read_b64
// with immediate offset (was 4x ds_read_u16 + or/shl + masks). Masks dropped
// entirely: kappa-packed A has zeros at k>=9, garbage*0=0 (all data finite).
// Phases 2+3 unchanged (bf16 MFMA, B hi+lo, C/D-native z + tr_b16 reads).

typedef float f4v  __attribute__((ext_vector_type(4)));
typedef short s8v  __attribute__((ext_vector_type(8)));
typedef _Float16 h8v __attribute__((ext_vector_type(8)));
typedef unsigned u2v __attribute__((ext_vector_type(2)));
typedef unsigned u4v __attribute__((ext_vector_type(4)));

constexpr int NG = 14, GI = 9, FH = 128, AD = 15;
constexpr int SLICE = 7712;   // slice byte stride (7680 + 32 bank skew)

__device__ __forceinline__ unsigned short f2bf(float f) {
    unsigned u = __builtin_bit_cast(unsigned, f);
    return (unsigned short)((u + 0x7fffu + ((u >> 16) & 1u)) >> 16);
}
__device__ __forceinline__ float bf2f(unsigned short h) {
    return __builtin_bit_cast(float, (unsigned)h << 16);
}
__device__ __forceinline__ f4v load4u(const float* p) {
    f4v v; __builtin_memcpy(&v, p, 16); return v;
}
__device__ __forceinline__ unsigned pkh(float a, float b) {
    return __builtin_bit_cast(unsigned, __builtin_amdgcn_cvt_pkrtz(a, b));
}
__device__ __forceinline__ unsigned pkbf(float a, float b) {
    unsigned r;
    asm("v_cvt_pk_bf16_f32 %0, %1, %2" : "=v"(r) : "v"(a), "v"(b));
    return r;
}

// pk layout (shorts): W3h[0,8192) W3l[8192,16384) W4h[16384,20480)
// W4l[20480,24576) W1T[24576,25088) W2T[25088,25600)
__global__ void pack_kernel(const float* __restrict__ W3,
                            const float* __restrict__ W4,
                            const float* __restrict__ W1,
                            const float* __restrict__ W2,
                            unsigned short* __restrict__ pk) {
    unsigned short* W3h = pk;
    unsigned short* W3l = pk + 8192;
    unsigned short* W4h = pk + 16384;
    unsigned short* W4l = pk + 20480;
    int t = blockIdx.x * 256 + threadIdx.x;
    if (t < 8192) {
        int j = t & 7, l = (t >> 3) & 63, nt = (t >> 9) & 7, kt = t >> 12;
        int k = kt * 32 + (l >> 4) * 8 + j, n = nt * 16 + (l & 15);
        float v = (k < 57) ? W3[k * FH + n] : 0.f;
        unsigned short h = f2bf(v);
        W3h[t] = h;
        W3l[t] = f2bf(v - bf2f(h));
    }
    if (t < 4096) {
        int j = t & 7, l = (t >> 3) & 63, nt = (t >> 9) & 1, kt = t >> 10;
        int k = kt * 32 + (l >> 4) * 8 + j, n = nt * 16 + (l & 15);
        float v = (n < 30) ? W4[k * 30 + n] : 0.f;
        unsigned short h = f2bf(v);
        W4h[t] = h;
        W4l[t] = f2bf(v - bf2f(h));
    }
    if (t < 512) {   // W1T + W2T A-frags, kappa(p,j)
        int l = t >> 3, j = t & 7;
        int p = l >> 4, m = l & 15;
        int k = (j < 4) ? (p * 4 + j) : (16 + p * 4 + (j - 4));
        float v1 = (k < GI) ? W1[k * 16 + m] : 0.f;          // W1 [9][16]
        float v2 = (k < 16 && m < 4) ? W2[k * 4 + m] : 0.f;  // W2 [16][4]
        _Float16 h1 = (_Float16)v1, h2 = (_Float16)v2;
        pk[24576 + t] = __builtin_bit_cast(unsigned short, h1);
        pk[25088 + t] = __builtin_bit_cast(unsigned short, h2);
    }
}

__global__ __launch_bounds__(256, 4) void actor_fused(
    const float* __restrict__ x,     // [B,126]
    const float* __restrict__ sale,  // [B,1]
    const float* __restrict__ b1,    // [16]
    const float* __restrict__ b2,    // [4]
    const float* __restrict__ b3,    // [128]
    const float* __restrict__ b4,    // [30]
    const unsigned short* __restrict__ pk,
    float* __restrict__ om, float* __restrict__ os)
{
    // xz 23104 B. Life 1: x fp16 p-slices (base p*SLICE, [64 rows][14 g][4]).
    //   Life 2 (after bar 1): z bf16 tiled (first 16384 B).
    // sh 8192 B: s bf16 [64][64] row-swizzled.
    __shared__ unsigned short xz[11552];
    __shared__ unsigned short sh[4096];

    const int tid  = threadIdx.x;
    const int wv   = __builtin_amdgcn_readfirstlane(tid >> 6);  // wave 0..3
    const int lane = tid & 63;
    const int row0 = blockIdx.x * 64;
    const int p    = lane >> 4;
    const int col  = lane & 15;

    // ---- wave-private x stage into p-slices: 224 (row,g) units per wave ----
    {
        const float* xw0 = x + (size_t)(row0 + 16 * wv) * (NG * GI);
        #pragma unroll
        for (int i = 0; i < 4; ++i) {
            int unit = i * 64 + lane;
            if (i < 3 || lane < 32) {           // 224 units
                int rl = (unit * 149797) >> 21;  // unit / 14
                int g  = unit - rl * 14;
                const float* xs = xw0 + rl * 126 + g * 9;
                f4v a = load4u(xs);
                f4v b = load4u(xs + 4);
                float c = xs[8];
                int bo = (16 * wv + rl) * 120 + g * 8;
                *(u2v*)((char*)xz + bo) = (u2v){pkh(a[0], a[1]), pkh(a[2], a[3])};
                *(u2v*)((char*)xz + SLICE + bo) = (u2v){pkh(b[0], b[1]), pkh(b[2], b[3])};
                *(u2v*)((char*)xz + 2 * SLICE + bo) = (u2v){pkh(c, 0.f), 0u};
            }
        }
    }
    // sale (k=56) + zero K-pad (k=57..63) for this wave's 16 rows
    if (lane < 16) {
        int r = 16 * wv + lane;
        float sv = sale[row0 + r];
        int byt = (r * 128 + 112) ^ ((r & 7) << 4);
        *(unsigned short*)((char*)sh + byt) = f2bf(sv);
        #pragma unroll
        for (int kk = 57; kk < 64; ++kk) {
            int bb = (r * 128 + kk * 2) ^ ((r & 7) << 4);
            *(unsigned short*)((char*)sh + bb) = 0;
        }
    }

    // ---- phase 1: virtual-row MFMA; wave wv owns rows 16wv..16wv+15 ----
    const int r1 = 16 * wv + col;
    const h8v w1t = __builtin_bit_cast(h8v, *(const s8v*)(pk + 24576 + lane * 8));
    const h8v w2t = __builtin_bit_cast(h8v, *(const s8v*)(pk + 25088 + lane * 8));
    const f4v b1f = load4u(b1 + p * 4);     // C-init rows h = p*4..p*4+3
    const f4v b2f = load4u(b2);             // valid for p==0 lanes
    const int psl = (p < 2) ? p : 2;        // p=3 clamps to slice 2 (A=0 kills)
    const char* xb8 = (char*)xz + psl * SLICE + r1 * 120;
    const int sbase = r1 * 128;
    const int ssw   = (r1 & 7) << 4;

    #pragma unroll
    for (int g = 0; g < NG; ++g) {
        u2v d = *(const u2v*)(xb8 + g * 8);       // ds_read_b64, imm offset
        h8v xb = __builtin_bit_cast(h8v, (u4v){d[0], d[1], 0u, 0u});
        f4v ha = __builtin_amdgcn_mfma_f32_16x16x32_f16(w1t, xb, b1f, 0, 0, 0);
        float h0 = fmaxf(ha[0], 0.f), h1 = fmaxf(ha[1], 0.f);
        float h2 = fmaxf(ha[2], 0.f), h3 = fmaxf(ha[3], 0.f);
        h8v hb = __builtin_bit_cast(h8v, (u4v){pkh(h0, h1), pkh(h2, h3), 0u, 0u});
        f4v sa = __builtin_amdgcn_mfma_f32_16x16x32_f16(w2t, hb, b2f, 0, 0, 0);
        float s0 = fmaxf(sa[0], 0.f), s1 = fmaxf(sa[1], 0.f);
        float s2 = fmaxf(sa[2], 0.f), s3 = fmaxf(sa[3], 0.f);
        unsigned q0 = pkbf(s0, s1), q1 = pkbf(s2, s3);
        if (p == 0) {
            int byt = (sbase + g * 8) ^ ssw;
            *(u2v*)((char*)sh + byt) = (u2v){q0, q1};
        }
    }

    __syncthreads();   // bar 1: all s ready; x region now dead

    // ---------------- phase 2: z[64,128] = s[64,64] @ W3  (MFMA) ----------
    const s8v* W3hv = (const s8v*)pk;
    const s8v* W3lv = (const s8v*)(pk + 8192);
    s8v bh[2][2], bl[2][2];
    #pragma unroll
    for (int kt = 0; kt < 2; ++kt)
        #pragma unroll
        for (int ntl = 0; ntl < 2; ++ntl) {
            int nt = 2 * wv + ntl;
            bh[kt][ntl] = W3hv[(kt * 8 + nt) * 64 + lane];
            bl[kt][ntl] = W3lv[(kt * 8 + nt) * 64 + lane];
        }
    f4v acc[4][2];
    #pragma unroll
    for (int ntl = 0; ntl < 2; ++ntl) {
        float bv = b3[32 * wv + ntl * 16 + col];
        #pragma unroll
        for (int mt = 0; mt < 4; ++mt) acc[mt][ntl] = (f4v){bv, bv, bv, bv};
    }
    #pragma unroll
    for (int kt = 0; kt < 2; ++kt) {
        s8v ah[4];
        #pragma unroll
        for (int mt = 0; mt < 4; ++mt) {
            int rr = mt * 16 + col;
            int byt = (rr * 128 + kt * 64 + p * 16) ^ ((rr & 7) << 4);
            ah[mt] = *(const s8v*)((char*)sh + byt);
        }
        #pragma unroll
        for (int mt = 0; mt < 4; ++mt)
            #pragma unroll
            for (int ntl = 0; ntl < 2; ++ntl) {
                acc[mt][ntl] = __builtin_amdgcn_mfma_f32_16x16x32_bf16(ah[mt], bh[kt][ntl], acc[mt][ntl], 0, 0, 0);
                acc[mt][ntl] = __builtin_amdgcn_mfma_f32_16x16x32_bf16(ah[mt], bl[kt][ntl], acc[mt][ntl], 0, 0, 0);
            }
    }
    // stage relu(z) into C/D-native tiled layout (2 cvt_pk + b64 per frag)
    #pragma unroll
    for (int mt = 0; mt < 4; ++mt)
        #pragma unroll
        for (int ntl = 0; ntl < 2; ++ntl) {
            int kk  = ntl * 16 + col;               // K & 31 (chunk = wv)
            int tau = (kk & 4) ? 4 + (kk >> 3) : (kk >> 3);
            int eidx = mt * 2048 + wv * 512 + tau * 64 + (kk & 3) * 16 + (p << 2);
            float v0 = fmaxf(acc[mt][ntl][0], 0.f);
            float v1 = fmaxf(acc[mt][ntl][1], 0.f);
            float v2 = fmaxf(acc[mt][ntl][2], 0.f);
            float v3 = fmaxf(acc[mt][ntl][3], 0.f);
            *(u2v*)(xz + eidx) = (u2v){pkbf(v0, v1), pkbf(v2, v3)};
        }

    __syncthreads();   // bar 2: z ready

    // ---- phase 3: out[64,30] = z @ W4; A-frags via ds_read_b64_tr_b16 ----
    const s8v* W4hv = (const s8v*)(pk + 16384);
    const s8v* W4lv = (const s8v*)(pk + 20480);
    const int mq   = __builtin_amdgcn_readfirstlane(wv >> 1);  // row-half
    const int nq   = __builtin_amdgcn_readfirstlane(wv & 1);   // col-half
    const int ocol = nq * 16 + col;
    const float b4i = (ocol < 30) ? b4[ocol] : 0.f;

    s8v wh[4], wl[4];
    #pragma unroll
    for (int kt = 0; kt < 4; ++kt) {
        wh[kt] = W4hv[(kt * 2 + nq) * 64 + lane];
        wl[kt] = W4lv[(kt * 2 + nq) * 64 + lane];
    }
    unsigned base = (unsigned)(size_t)&xz[0] + (unsigned)(2 * mq) * 4096u
                  + (unsigned)(lane * 8);
    u2v f0[4][2], f1[4][2];
    #pragma unroll
    for (int c = 0; c < 4; ++c) {
        unsigned a0 = base + c * 1024;
        unsigned a1 = a0 + 4096;
        asm volatile("ds_read_b64_tr_b16 %0, %1" : "=v"(f0[c][0]) : "v"(a0));
        asm volatile("ds_read_b64_tr_b16 %0, %1 offset:512" : "=v"(f0[c][1]) : "v"(a0));
        asm volatile("ds_read_b64_tr_b16 %0, %1" : "=v"(f1[c][0]) : "v"(a1));
        asm volatile("ds_read_b64_tr_b16 %0, %1 offset:512" : "=v"(f1[c][1]) : "v"(a1));
    }
    asm volatile("s_waitcnt lgkmcnt(0)" ::: "memory");
    __builtin_amdgcn_sched_barrier(0);

    f4v oa0 = (f4v){b4i, b4i, b4i, b4i};
    f4v oa1 = oa0;
    #pragma unroll
    for (int kt = 0; kt < 4; ++kt) {
        s8v z0 = __builtin_bit_cast(s8v,
            (u4v){f0[kt][0][0], f0[kt][0][1], f0[kt][1][0], f0[kt][1][1]});
        s8v z1 = __builtin_bit_cast(s8v,
            (u4v){f1[kt][0][0], f1[kt][0][1], f1[kt][1][0], f1[kt][1][1]});
        oa0 = __builtin_amdgcn_mfma_f32_16x16x32_bf16(z0, wh[kt], oa0, 0, 0, 0);
        oa0 = __builtin_amdgcn_mfma_f32_16x16x32_bf16(z0, wl[kt], oa0, 0, 0, 0);
        oa1 = __builtin_amdgcn_mfma_f32_16x16x32_bf16(z1, wh[kt], oa1, 0, 0, 0);
        oa1 = __builtin_amdgcn_mfma_f32_16x16x32_bf16(z1, wl[kt], oa1, 0, 0, 0);
    }
    #pragma unroll
    for (int mi = 0; mi < 2; ++mi) {
        f4v oa = mi ? oa1 : oa0;
        #pragma unroll
        for (int i = 0; i < 4; ++i) {
            int grow = row0 + mq * 32 + mi * 16 + p * 4 + i;
            float v = oa[i];
            if (ocol < AD) {
                float tc = fminf(fmaxf(v, -20.f), 20.f);
                float e = __expf(2.f * tc);
                om[(size_t)grow * AD + ocol] = (e - 1.f) / (e + 1.f);
            } else if (ocol < 2 * AD) {
                os[(size_t)grow * AD + (ocol - AD)] = __expf(v);
            }
        }
    }
}

extern "C" void kernel_launch(void* const* d_in, const int* in_sizes, int n_in,
                              void* d_out, int out_size, void* d_ws, size_t ws_size,
                              hipStream_t stream) {
    const float* x    = (const float*)d_in[0];
    const float* sale = (const float*)d_in[1];
    const float* W1   = (const float*)d_in[2];
    const float* b1   = (const float*)d_in[3];
    const float* W2   = (const float*)d_in[4];
    const float* b2   = (const float*)d_in[5];
    const float* W3   = (const float*)d_in[6];
    const float* b3   = (const float*)d_in[7];
    const float* W4   = (const float*)d_in[8];
    const float* b4   = (const float*)d_in[9];

    int B = in_sizes[1];                       // sale_predictions is [B,1]
    float* om = (float*)d_out;                 // action_mean flat [B*15]
    float* os = om + (size_t)B * AD;           // action_std  flat [B*15]
    unsigned short* pk = (unsigned short*)d_ws;  // 25600 shorts = 51.2 KB

    pack_kernel<<<32, 256, 0, stream>>>(W3, W4, W1, W2, pk);
    actor_fused<<<B / 64, 256, 0, stream>>>(x, sale, b1, b2, b3, b4,
                                            pk, om, os);
}

// Round 21
// 45.798 us; speedup vs baseline: 1.0965x; 1.0780x over previous
//
#include <hip/hip_runtime.h>

// Actor MLP, B=262144 rows, fp32 in/out. All three GEMM stages on MFMA.
// R21 = R20 + three latency/occupancy fixes:
//  1. slice 2 (k8) compacted to [64][32B] u16 (2KB, was 7.7KB) -> LDS 25664
//     -> 6 blocks/CU (was 5).
//  2. kappa remap: x[k8] feeds p0's j=4 B-slot (A-pack holds W1[8] there,
//     p2 j0 slot zeroed) -> phase-1 read = unconditional b64 + u16, NO masks;
//     p>=2 lanes read finite garbage killed by A=0.
//  3. weight B-frags hoisted across barriers: bh/bl+b3 at kernel top (latency
//     under staging+phase1); wh/wl+b4 after phase-2 MFMAs (under z-staging).
// Phases 2+3 unchanged (bf16 MFMA, B hi+lo, C/D-native z + tr_b16 reads).

typedef float f4v  __attribute__((ext_vector_type(4)));
typedef short s8v  __attribute__((ext_vector_type(8)));
typedef _Float16 h8v __attribute__((ext_vector_type(8)));
typedef unsigned u2v __attribute__((ext_vector_type(2)));
typedef unsigned u4v __attribute__((ext_vector_type(4)));

constexpr int NG = 14, GI = 9, FH = 128, AD = 15;
constexpr int SLICE = 7712;    // slice 0/1 byte stride (120B/row x 64 + skew)
constexpr int S2OFF = 15424;   // compact k8 slice: [64][32B] u16 per group

__device__ __forceinline__ unsigned short f2bf(float f) {
    unsigned u = __builtin_bit_cast(unsigned, f);
    return (unsigned short)((u + 0x7fffu + ((u >> 16) & 1u)) >> 16);
}
__device__ __forceinline__ float bf2f(unsigned short h) {
    return __builtin_bit_cast(float, (unsigned)h << 16);
}
__device__ __forceinline__ f4v load4u(const float* p) {
    f4v v; __builtin_memcpy(&v, p, 16); return v;
}
__device__ __forceinline__ unsigned pkh(float a, float b) {
    return __builtin_bit_cast(unsigned, __builtin_amdgcn_cvt_pkrtz(a, b));
}
__device__ __forceinline__ unsigned pkbf(float a, float b) {
    unsigned r;
    asm("v_cvt_pk_bf16_f32 %0, %1, %2" : "=v"(r) : "v"(a), "v"(b));
    return r;
}

// pk layout (shorts): W3h[0,8192) W3l[8192,16384) W4h[16384,20480)
// W4l[20480,24576) W1T[24576,25088) W2T[25088,25600)
__global__ void pack_kernel(const float* __restrict__ W3,
                            const float* __restrict__ W4,
                            const float* __restrict__ W1,
                            const float* __restrict__ W2,
                            unsigned short* __restrict__ pk) {
    unsigned short* W3h = pk;
    unsigned short* W3l = pk + 8192;
    unsigned short* W4h = pk + 16384;
    unsigned short* W4l = pk + 20480;
    int t = blockIdx.x * 256 + threadIdx.x;
    if (t < 8192) {
        int j = t & 7, l = (t >> 3) & 63, nt = (t >> 9) & 7, kt = t >> 12;
        int k = kt * 32 + (l >> 4) * 8 + j, n = nt * 16 + (l & 15);
        float v = (k < 57) ? W3[k * FH + n] : 0.f;
        unsigned short h = f2bf(v);
        W3h[t] = h;
        W3l[t] = f2bf(v - bf2f(h));
    }
    if (t < 4096) {
        int j = t & 7, l = (t >> 3) & 63, nt = (t >> 9) & 1, kt = t >> 10;
        int k = kt * 32 + (l >> 4) * 8 + j, n = nt * 16 + (l & 15);
        float v = (n < 30) ? W4[k * 30 + n] : 0.f;
        unsigned short h = f2bf(v);
        W4h[t] = h;
        W4l[t] = f2bf(v - bf2f(h));
    }
    if (t < 512) {   // W1T/W2T A-frags
        int l = t >> 3, j = t & 7;
        int p = l >> 4, m = l & 15;
        // layer1: p0 j0-3 -> k=j; p0 j4 -> k=8; p1 j0-3 -> k=4+j; else 0.
        float v1 = 0.f;
        if (p == 0 && j < 4)       v1 = W1[j * 16 + m];
        else if (p == 0 && j == 4) v1 = W1[8 * 16 + m];
        else if (p == 1 && j < 4)  v1 = W1[(4 + j) * 16 + m];
        // layer2: kappa2(p,j) = 4p+j for j<4 (h-frag slot order), else 0.
        int k2 = (j < 4) ? (p * 4 + j) : 99;
        float v2 = (k2 < 16 && m < 4) ? W2[k2 * 4 + m] : 0.f;
        _Float16 h1 = (_Float16)v1, h2 = (_Float16)v2;
        pk[24576 + t] = __builtin_bit_cast(unsigned short, h1);
        pk[25088 + t] = __builtin_bit_cast(unsigned short, h2);
    }
}

__global__ __launch_bounds__(256, 4) void actor_fused(
    const float* __restrict__ x,     // [B,126]
    const float* __restrict__ sale,  // [B,1]
    const float* __restrict__ b1,    // [16]
    const float* __restrict__ b2,    // [4]
    const float* __restrict__ b3,    // [128]
    const float* __restrict__ b4,    // [30]
    const unsigned short* __restrict__ pk,
    float* __restrict__ om, float* __restrict__ os)
{
    // xz 17472 B. Life 1: x fp16 slices 0/1 (k0-3,k4-7; 120B/row) + compact
    //   k8 slice @15424 ([64][32B] u16). Life 2 (after bar 1): z bf16 tiled
    //   (first 16384 B). sh 8192 B: s bf16 [64][64] row-swizzled.
    __shared__ unsigned short xz[8736];
    __shared__ unsigned short sh[4096];

    const int tid  = threadIdx.x;
    const int wv   = __builtin_amdgcn_readfirstlane(tid >> 6);  // wave 0..3
    const int lane = tid & 63;
    const int row0 = blockIdx.x * 64;
    const int p    = lane >> 4;
    const int col  = lane & 15;

    // ---- hoisted phase-2 weight B-frags + b3 (latency hides under phase 1) --
    const s8v* W3hv = (const s8v*)pk;
    const s8v* W3lv = (const s8v*)(pk + 8192);
    s8v bh[2][2], bl[2][2];
    #pragma unroll
    for (int kt = 0; kt < 2; ++kt)
        #pragma unroll
        for (int ntl = 0; ntl < 2; ++ntl) {
            int nt = 2 * wv + ntl;
            bh[kt][ntl] = W3hv[(kt * 8 + nt) * 64 + lane];
            bl[kt][ntl] = W3lv[(kt * 8 + nt) * 64 + lane];
        }
    const float bv0 = b3[32 * wv + col];
    const float bv1 = b3[32 * wv + 16 + col];

    // ---- wave-private x stage: 224 (row,g) units per wave ----
    {
        const float* xw0 = x + (size_t)(row0 + 16 * wv) * (NG * GI);
        #pragma unroll
        for (int i = 0; i < 4; ++i) {
            int unit = i * 64 + lane;
            if (i < 3 || lane < 32) {           // 224 units
                int rl = (unit * 149797) >> 21;  // unit / 14
                int g  = unit - rl * 14;
                const float* xs = xw0 + rl * 126 + g * 9;
                f4v a = load4u(xs);
                f4v b = load4u(xs + 4);
                float c = xs[8];
                int r  = 16 * wv + rl;
                int bo = r * 120 + g * 8;
                *(u2v*)((char*)xz + bo) = (u2v){pkh(a[0], a[1]), pkh(a[2], a[3])};
                *(u2v*)((char*)xz + SLICE + bo) = (u2v){pkh(b[0], b[1]), pkh(b[2], b[3])};
                _Float16 ch = (_Float16)c;
                *(unsigned short*)((char*)xz + S2OFF + r * 32 + g * 2) =
                    __builtin_bit_cast(unsigned short, ch);
            }
        }
    }
    // sale (k=56) + zero K-pad (k=57..63) for this wave's 16 rows
    if (lane < 16) {
        int r = 16 * wv + lane;
        float sv = sale[row0 + r];
        int byt = (r * 128 + 112) ^ ((r & 7) << 4);
        *(unsigned short*)((char*)sh + byt) = f2bf(sv);
        #pragma unroll
        for (int kk = 57; kk < 64; ++kk) {
            int bb = (r * 128 + kk * 2) ^ ((r & 7) << 4);
            *(unsigned short*)((char*)sh + bb) = 0;
        }
    }

    // ---- phase 1: virtual-row MFMA; wave wv owns rows 16wv..16wv+15 ----
    const int r1 = 16 * wv + col;
    const h8v w1t = __builtin_bit_cast(h8v, *(const s8v*)(pk + 24576 + lane * 8));
    const h8v w2t = __builtin_bit_cast(h8v, *(const s8v*)(pk + 25088 + lane * 8));
    const f4v b1f = load4u(b1 + p * 4);     // C-init rows h = p*4..p*4+3
    const f4v b2f = load4u(b2);             // valid for p==0 lanes
    // p0 -> slice0 (k0-3); p1 -> slice1 (k4-7); p2/p3 -> slice1 garbage
    // (finite, killed by A=0). k8 u16 read by ALL lanes -> p0's j4 slot
    // (A(p0,j4)=W1[8]; other lanes' j4 A=0).
    const char* xb8 = (char*)xz + (p ? SLICE : 0) + r1 * 120;
    const char* s2p = (char*)xz + S2OFF + r1 * 32;
    const int sbase = r1 * 128;
    const int ssw   = (r1 & 7) << 4;

    #pragma unroll
    for (int g = 0; g < NG; ++g) {
        u2v d = *(const u2v*)(xb8 + g * 8);                    // ds_read_b64
        unsigned k8 = *(const unsigned short*)(s2p + g * 2);   // ds_read_u16
        h8v xb = __builtin_bit_cast(h8v, (u4v){d[0], d[1], k8, 0u});
        f4v ha = __builtin_amdgcn_mfma_f32_16x16x32_f16(w1t, xb, b1f, 0, 0, 0);
        float h0 = fmaxf(ha[0], 0.f), h1 = fmaxf(ha[1], 0.f);
        float h2 = fmaxf(ha[2], 0.f), h3 = fmaxf(ha[3], 0.f);
        h8v hb = __builtin_bit_cast(h8v, (u4v){pkh(h0, h1), pkh(h2, h3), 0u, 0u});
        f4v sa = __builtin_amdgcn_mfma_f32_16x16x32_f16(w2t, hb, b2f, 0, 0, 0);
        float s0 = fmaxf(sa[0], 0.f), s1 = fmaxf(sa[1], 0.f);
        float s2 = fmaxf(sa[2], 0.f), s3 = fmaxf(sa[3], 0.f);
        unsigned q0 = pkbf(s0, s1), q1 = pkbf(s2, s3);
        if (p == 0) {
            int byt = (sbase + g * 8) ^ ssw;
            *(u2v*)((char*)sh + byt) = (u2v){q0, q1};
        }
    }

    __syncthreads();   // bar 1: all s ready; x region now dead

    // ---------------- phase 2: z[64,128] = s[64,64] @ W3  (MFMA) ----------
    f4v acc[4][2];
    #pragma unroll
    for (int mt = 0; mt < 4; ++mt) {
        acc[mt][0] = (f4v){bv0, bv0, bv0, bv0};
        acc[mt][1] = (f4v){bv1, bv1, bv1, bv1};
    }
    #pragma unroll
    for (int kt = 0; kt < 2; ++kt) {
        s8v ah[4];
        #pragma unroll
        for (int mt = 0; mt < 4; ++mt) {
            int rr = mt * 16 + col;
            int byt = (rr * 128 + kt * 64 + p * 16) ^ ((rr & 7) << 4);
            ah[mt] = *(const s8v*)((char*)sh + byt);
        }
        #pragma unroll
        for (int mt = 0; mt < 4; ++mt)
            #pragma unroll
            for (int ntl = 0; ntl < 2; ++ntl) {
                acc[mt][ntl] = __builtin_amdgcn_mfma_f32_16x16x32_bf16(ah[mt], bh[kt][ntl], acc[mt][ntl], 0, 0, 0);
                acc[mt][ntl] = __builtin_amdgcn_mfma_f32_16x16x32_bf16(ah[mt], bl[kt][ntl], acc[mt][ntl], 0, 0, 0);
            }
    }

    // ---- hoisted phase-3 weight B-frags + b4 (latency hides under z-stage) --
    const s8v* W4hv = (const s8v*)(pk + 16384);
    const s8v* W4lv = (const s8v*)(pk + 20480);
    const int mq   = __builtin_amdgcn_readfirstlane(wv >> 1);  // row-half
    const int nq   = __builtin_amdgcn_readfirstlane(wv & 1);   // col-half
    const int ocol = nq * 16 + col;
    s8v wh[4], wl[4];
    #pragma unroll
    for (int kt = 0; kt < 4; ++kt) {
        wh[kt] = W4hv[(kt * 2 + nq) * 64 + lane];
        wl[kt] = W4lv[(kt * 2 + nq) * 64 + lane];
    }
    const float b4i = (ocol < 30) ? b4[ocol] : 0.f;

    // stage relu(z) into C/D-native tiled layout (2 cvt_pk + b64 per frag)
    #pragma unroll
    for (int mt = 0; mt < 4; ++mt)
        #pragma unroll
        for (int ntl = 0; ntl < 2; ++ntl) {
            int kk  = ntl * 16 + col;               // K & 31 (chunk = wv)
            int tau = (kk & 4) ? 4 + (kk >> 3) : (kk >> 3);
            int eidx = mt * 2048 + wv * 512 + tau * 64 + (kk & 3) * 16 + (p << 2);
            float v0 = fmaxf(acc[mt][ntl][0], 0.f);
            float v1 = fmaxf(acc[mt][ntl][1], 0.f);
            float v2 = fmaxf(acc[mt][ntl][2], 0.f);
            float v3 = fmaxf(acc[mt][ntl][3], 0.f);
            *(u2v*)(xz + eidx) = (u2v){pkbf(v0, v1), pkbf(v2, v3)};
        }

    __syncthreads();   // bar 2: z ready

    // ---- phase 3: out[64,30] = z @ W4; A-frags via ds_read_b64_tr_b16 ----
    unsigned base = (unsigned)(size_t)&xz[0] + (unsigned)(2 * mq) * 4096u
                  + (unsigned)(lane * 8);
    u2v f0[4][2], f1[4][2];
    #pragma unroll
    for (int c = 0; c < 4; ++c) {
        unsigned a0 = base + c * 1024;
        unsigned a1 = a0 + 4096;
        asm volatile("ds_read_b64_tr_b16 %0, %1" : "=v"(f0[c][0]) : "v"(a0));
        asm volatile("ds_read_b64_tr_b16 %0, %1 offset:512" : "=v"(f0[c][1]) : "v"(a0));
        asm volatile("ds_read_b64_tr_b16 %0, %1" : "=v"(f1[c][0]) : "v"(a1));
        asm volatile("ds_read_b64_tr_b16 %0, %1 offset:512" : "=v"(f1[c][1]) : "v"(a1));
    }
    asm volatile("s_waitcnt lgkmcnt(0)" ::: "memory");
    __builtin_amdgcn_sched_barrier(0);

    f4v oa0 = (f4v){b4i, b4i, b4i, b4i};
    f4v oa1 = oa0;
    #pragma unroll
    for (int kt = 0; kt < 4; ++kt) {
        s8v z0 = __builtin_bit_cast(s8v,
            (u4v){f0[kt][0][0], f0[kt][0][1], f0[kt][1][0], f0[kt][1][1]});
        s8v z1 = __builtin_bit_cast(s8v,
            (u4v){f1[kt][0][0], f1[kt][0][1], f1[kt][1][0], f1[kt][1][1]});
        oa0 = __builtin_amdgcn_mfma_f32_16x16x32_bf16(z0, wh[kt], oa0, 0, 0, 0);
        oa0 = __builtin_amdgcn_mfma_f32_16x16x32_bf16(z0, wl[kt], oa0, 0, 0, 0);
        oa1 = __builtin_amdgcn_mfma_f32_16x16x32_bf16(z1, wh[kt], oa1, 0, 0, 0);
        oa1 = __builtin_amdgcn_mfma_f32_16x16x32_bf16(z1, wl[kt], oa1, 0, 0, 0);
    }
    #pragma unroll
    for (int mi = 0; mi < 2; ++mi) {
        f4v oa = mi ? oa1 : oa0;
        #pragma unroll
        for (int i = 0; i < 4; ++i) {
            int grow = row0 + mq * 32 + mi * 16 + p * 4 + i;
            float v = oa[i];
            if (ocol < AD) {
                float tc = fminf(fmaxf(v, -20.f), 20.f);
                float e = __expf(2.f * tc);
                om[(size_t)grow * AD + ocol] = (e - 1.f) / (e + 1.f);
            } else if (ocol < 2 * AD) {
                os[(size_t)grow * AD + (ocol - AD)] = __expf(v);
            }
        }
    }
}

extern "C" void kernel_launch(void* const* d_in, const int* in_sizes, int n_in,
                              void* d_out, int out_size, void* d_ws, size_t ws_size,
                              hipStream_t stream) {
    const float* x    = (const float*)d_in[0];
    const float* sale = (const float*)d_in[1];
    const float* W1   = (const float*)d_in[2];
    const float* b1   = (const float*)d_in[3];
    const float* W2   = (const float*)d_in[4];
    const float* b2   = (const float*)d_in[5];
    const float* W3   = (const float*)d_in[6];
    const float* b3   = (const float*)d_in[7];
    const float* W4   = (const float*)d_in[8];
    const float* b4   = (const float*)d_in[9];

    int B = in_sizes[1];                       // sale_predictions is [B,1]
    float* om = (float*)d_out;                 // action_mean flat [B*15]
    float* os = om + (size_t)B * AD;           // action_std  flat [B*15]
    unsigned short* pk = (unsigned short*)d_ws;  // 25600 shorts = 51.2 KB

    pack_kernel<<<32, 256, 0, stream>>>(W3, W4, W1, W2, pk);
    actor_fused<<<B / 64, 256, 0, stream>>>(x, sale, b1, b2, b3, b4,
                                            pk, om, os);
}

// Round 22
// 44.841 us; speedup vs baseline: 1.1199x; 1.0213x over previous
//
#include <hip/hip_runtime.h>

// Actor MLP, B=262144 rows, fp32 in/out. All three GEMM stages on MFMA.
// R22 = R21 + phase-1 LDS consolidation:
//  - x slices back to 128B row stride with sh-style XOR swizzle
//    (off ^= (r&7)<<4): the row's 8 16B-slots are permuted bijectively;
//    x pairs occupy 7 slots, the k8 shorts live in the 8th (bytes 112+).
//  - phase-1 reads: 2 ds_read_b128 (all 14 k8) + 7 ds_read_b128 (2 groups
//    each) = 9 LDS reads/lane (was 28), all <=2-way bank (free).
//  - w1t/w2t/b1f/b2f hoisted to kernel top. LDS 24576 -> 6 blocks/CU.
// Phases 2+3 unchanged (bf16 MFMA, B hi+lo, C/D-native z + tr_b16 reads).

typedef float f4v  __attribute__((ext_vector_type(4)));
typedef short s8v  __attribute__((ext_vector_type(8)));
typedef _Float16 h8v __attribute__((ext_vector_type(8)));
typedef unsigned u2v __attribute__((ext_vector_type(2)));
typedef unsigned u4v __attribute__((ext_vector_type(4)));

constexpr int NG = 14, GI = 9, FH = 128, AD = 15;

__device__ __forceinline__ unsigned short f2bf(float f) {
    unsigned u = __builtin_bit_cast(unsigned, f);
    return (unsigned short)((u + 0x7fffu + ((u >> 16) & 1u)) >> 16);
}
__device__ __forceinline__ float bf2f(unsigned short h) {
    return __builtin_bit_cast(float, (unsigned)h << 16);
}
__device__ __forceinline__ f4v load4u(const float* p) {
    f4v v; __builtin_memcpy(&v, p, 16); return v;
}
__device__ __forceinline__ unsigned pkh(float a, float b) {
    return __builtin_bit_cast(unsigned, __builtin_amdgcn_cvt_pkrtz(a, b));
}
__device__ __forceinline__ unsigned pkbf(float a, float b) {
    unsigned r;
    asm("v_cvt_pk_bf16_f32 %0, %1, %2" : "=v"(r) : "v"(a), "v"(b));
    return r;
}

// pk layout (shorts): W3h[0,8192) W3l[8192,16384) W4h[16384,20480)
// W4l[20480,24576) W1T[24576,25088) W2T[25088,25600)
__global__ void pack_kernel(const float* __restrict__ W3,
                            const float* __restrict__ W4,
                            const float* __restrict__ W1,
                            const float* __restrict__ W2,
                            unsigned short* __restrict__ pk) {
    unsigned short* W3h = pk;
    unsigned short* W3l = pk + 8192;
    unsigned short* W4h = pk + 16384;
    unsigned short* W4l = pk + 20480;
    int t = blockIdx.x * 256 + threadIdx.x;
    if (t < 8192) {
        int j = t & 7, l = (t >> 3) & 63, nt = (t >> 9) & 7, kt = t >> 12;
        int k = kt * 32 + (l >> 4) * 8 + j, n = nt * 16 + (l & 15);
        float v = (k < 57) ? W3[k * FH + n] : 0.f;
        unsigned short h = f2bf(v);
        W3h[t] = h;
        W3l[t] = f2bf(v - bf2f(h));
    }
    if (t < 4096) {
        int j = t & 7, l = (t >> 3) & 63, nt = (t >> 9) & 1, kt = t >> 10;
        int k = kt * 32 + (l >> 4) * 8 + j, n = nt * 16 + (l & 15);
        float v = (n < 30) ? W4[k * 30 + n] : 0.f;
        unsigned short h = f2bf(v);
        W4h[t] = h;
        W4l[t] = f2bf(v - bf2f(h));
    }
    if (t < 512) {   // W1T/W2T A-frags
        int l = t >> 3, j = t & 7;
        int p = l >> 4, m = l & 15;
        // layer1: p0 j0-3 -> k=j; p0 j4 -> k=8; p1 j0-3 -> k=4+j; else 0.
        float v1 = 0.f;
        if (p == 0 && j < 4)       v1 = W1[j * 16 + m];
        else if (p == 0 && j == 4) v1 = W1[8 * 16 + m];
        else if (p == 1 && j < 4)  v1 = W1[(4 + j) * 16 + m];
        // layer2: kappa2(p,j) = 4p+j for j<4 (h-frag slot order), else 0.
        int k2 = (j < 4) ? (p * 4 + j) : 99;
        float v2 = (k2 < 16 && m < 4) ? W2[k2 * 4 + m] : 0.f;
        _Float16 h1 = (_Float16)v1, h2 = (_Float16)v2;
        pk[24576 + t] = __builtin_bit_cast(unsigned short, h1);
        pk[25088 + t] = __builtin_bit_cast(unsigned short, h2);
    }
}

__global__ __launch_bounds__(256, 4) void actor_fused(
    const float* __restrict__ x,     // [B,126]
    const float* __restrict__ sale,  // [B,1]
    const float* __restrict__ b1,    // [16]
    const float* __restrict__ b2,    // [4]
    const float* __restrict__ b3,    // [128]
    const float* __restrict__ b4,    // [30]
    const unsigned short* __restrict__ pk,
    float* __restrict__ om, float* __restrict__ os)
{
    // xz 16384 B. Life 1: x fp16 slice0 [0,8192) (k0-3 pairs + k8 g0-7 in
    //   slot 7), slice1 [8192,16384) (k4-7 pairs + k8 g8-13); rows 128B,
    //   XOR-swizzled. Life 2 (after bar 1): z bf16 tiled (all 16384 B).
    // sh 8192 B: s bf16 [64][64] row-swizzled.
    __shared__ unsigned short xz[8192];
    __shared__ unsigned short sh[4096];

    const int tid  = threadIdx.x;
    const int wv   = __builtin_amdgcn_readfirstlane(tid >> 6);  // wave 0..3
    const int lane = tid & 63;
    const int row0 = blockIdx.x * 64;
    const int p    = lane >> 4;
    const int col  = lane & 15;
    char* xzb = (char*)xz;

    // ---- hoisted phase-1 A-frags + biases ----
    const h8v w1t = __builtin_bit_cast(h8v, *(const s8v*)(pk + 24576 + lane * 8));
    const h8v w2t = __builtin_bit_cast(h8v, *(const s8v*)(pk + 25088 + lane * 8));
    const f4v b1f = load4u(b1 + p * 4);
    const f4v b2f = load4u(b2);
    // ---- hoisted phase-2 weight B-frags + b3 (latency hides under phase 1) --
    const s8v* W3hv = (const s8v*)pk;
    const s8v* W3lv = (const s8v*)(pk + 8192);
    s8v bh[2][2], bl[2][2];
    #pragma unroll
    for (int kt = 0; kt < 2; ++kt)
        #pragma unroll
        for (int ntl = 0; ntl < 2; ++ntl) {
            int nt = 2 * wv + ntl;
            bh[kt][ntl] = W3hv[(kt * 8 + nt) * 64 + lane];
            bl[kt][ntl] = W3lv[(kt * 8 + nt) * 64 + lane];
        }
    const float bv0 = b3[32 * wv + col];
    const float bv1 = b3[32 * wv + 16 + col];

    // ---- wave-private x stage: 224 (row,g) units per wave ----
    {
        const float* xw0 = x + (size_t)(row0 + 16 * wv) * (NG * GI);
        #pragma unroll
        for (int i = 0; i < 4; ++i) {
            int unit = i * 64 + lane;
            if (i < 3 || lane < 32) {           // 224 units
                int rl = (unit * 149797) >> 21;  // unit / 14
                int g  = unit - rl * 14;
                const float* xs = xw0 + rl * 126 + g * 9;
                f4v a = load4u(xs);
                f4v b = load4u(xs + 4);
                float c = xs[8];
                int r  = 16 * wv + rl;
                int sw = (r & 7) << 4;
                int rb = r * 128;
                *(u2v*)(xzb + (rb + ((g * 8) ^ sw))) =
                    (u2v){pkh(a[0], a[1]), pkh(a[2], a[3])};
                *(u2v*)(xzb + 8192 + (rb + ((g * 8) ^ sw))) =
                    (u2v){pkh(b[0], b[1]), pkh(b[2], b[3])};
                _Float16 ch = (_Float16)c;
                int k8off = (g < 8 ? 0 : 8192) + rb + ((112 + (g & 7) * 2) ^ sw);
                *(unsigned short*)(xzb + k8off) =
                    __builtin_bit_cast(unsigned short, ch);
            }
        }
    }
    // sale (k=56) + zero K-pad (k=57..63) for this wave's 16 rows
    if (lane < 16) {
        int r = 16 * wv + lane;
        float sv = sale[row0 + r];
        int byt = (r * 128 + 112) ^ ((r & 7) << 4);
        *(unsigned short*)((char*)sh + byt) = f2bf(sv);
        #pragma unroll
        for (int kk = 57; kk < 64; ++kk) {
            int bb = (r * 128 + kk * 2) ^ ((r & 7) << 4);
            *(unsigned short*)((char*)sh + bb) = 0;
        }
    }

    // ---- phase 1: virtual-row MFMA; wave wv owns rows 16wv..16wv+15 ----
    const int r1 = 16 * wv + col;
    const int ssw = (r1 & 7) << 4;
    const char* xrow = xzb + (p ? 8192 : 0) + r1 * 128;   // p>=2: garbage, A=0
    // all 14 k8 values: slot 7 of both slices of row r1
    const u4v k8A = *(const u4v*)(xzb + r1 * 128 + (112 ^ ssw));
    const u4v k8B = *(const u4v*)(xzb + 8192 + r1 * 128 + (112 ^ ssw));
    const int sbase = r1 * 128;

    #pragma unroll
    for (int gp = 0; gp < 7; ++gp) {
        u4v dv = *(const u4v*)(xrow + ((gp * 16) ^ ssw));   // ds_read_b128
        #pragma unroll
        for (int gi = 0; gi < 2; ++gi) {
            const int g = 2 * gp + gi;
            unsigned wk = (g < 8) ? k8A[g >> 1] : k8B[(g - 8) >> 1];
            unsigned k8v = (g & 1) ? (wk >> 16) : (wk & 0xffffu);
            h8v xb = __builtin_bit_cast(h8v,
                (u4v){dv[2 * gi], dv[2 * gi + 1], k8v, 0u});
            f4v ha = __builtin_amdgcn_mfma_f32_16x16x32_f16(w1t, xb, b1f, 0, 0, 0);
            float h0 = fmaxf(ha[0], 0.f), h1 = fmaxf(ha[1], 0.f);
            float h2 = fmaxf(ha[2], 0.f), h3 = fmaxf(ha[3], 0.f);
            h8v hb = __builtin_bit_cast(h8v,
                (u4v){pkh(h0, h1), pkh(h2, h3), 0u, 0u});
            f4v sa = __builtin_amdgcn_mfma_f32_16x16x32_f16(w2t, hb, b2f, 0, 0, 0);
            float s0 = fmaxf(sa[0], 0.f), s1 = fmaxf(sa[1], 0.f);
            float s2 = fmaxf(sa[2], 0.f), s3 = fmaxf(sa[3], 0.f);
            unsigned q0 = pkbf(s0, s1), q1 = pkbf(s2, s3);
            if (p == 0) {
                int byt = (sbase + g * 8) ^ ssw;
                *(u2v*)((char*)sh + byt) = (u2v){q0, q1};
            }
        }
    }

    __syncthreads();   // bar 1: all s ready; x region now dead

    // ---------------- phase 2: z[64,128] = s[64,64] @ W3  (MFMA) ----------
    f4v acc[4][2];
    #pragma unroll
    for (int mt = 0; mt < 4; ++mt) {
        acc[mt][0] = (f4v){bv0, bv0, bv0, bv0};
        acc[mt][1] = (f4v){bv1, bv1, bv1, bv1};
    }
    #pragma unroll
    for (int kt = 0; kt < 2; ++kt) {
        s8v ah[4];
        #pragma unroll
        for (int mt = 0; mt < 4; ++mt) {
            int rr = mt * 16 + col;
            int byt = (rr * 128 + kt * 64 + p * 16) ^ ((rr & 7) << 4);
            ah[mt] = *(const s8v*)((char*)sh + byt);
        }
        #pragma unroll
        for (int mt = 0; mt < 4; ++mt)
            #pragma unroll
            for (int ntl = 0; ntl < 2; ++ntl) {
                acc[mt][ntl] = __builtin_amdgcn_mfma_f32_16x16x32_bf16(ah[mt], bh[kt][ntl], acc[mt][ntl], 0, 0, 0);
                acc[mt][ntl] = __builtin_amdgcn_mfma_f32_16x16x32_bf16(ah[mt], bl[kt][ntl], acc[mt][ntl], 0, 0, 0);
            }
    }

    // ---- hoisted phase-3 weight B-frags + b4 (latency hides under z-stage) --
    const s8v* W4hv = (const s8v*)(pk + 16384);
    const s8v* W4lv = (const s8v*)(pk + 20480);
    const int mq   = __builtin_amdgcn_readfirstlane(wv >> 1);  // row-half
    const int nq   = __builtin_amdgcn_readfirstlane(wv & 1);   // col-half
    const int ocol = nq * 16 + col;
    s8v wh[4], wl[4];
    #pragma unroll
    for (int kt = 0; kt < 4; ++kt) {
        wh[kt] = W4hv[(kt * 2 + nq) * 64 + lane];
        wl[kt] = W4lv[(kt * 2 + nq) * 64 + lane];
    }
    const float b4i = (ocol < 30) ? b4[ocol] : 0.f;

    // stage relu(z) into C/D-native tiled layout (2 cvt_pk + b64 per frag)
    #pragma unroll
    for (int mt = 0; mt < 4; ++mt)
        #pragma unroll
        for (int ntl = 0; ntl < 2; ++ntl) {
            int kk  = ntl * 16 + col;               // K & 31 (chunk = wv)
            int tau = (kk & 4) ? 4 + (kk >> 3) : (kk >> 3);
            int eidx = mt * 2048 + wv * 512 + tau * 64 + (kk & 3) * 16 + (p << 2);
            float v0 = fmaxf(acc[mt][ntl][0], 0.f);
            float v1 = fmaxf(acc[mt][ntl][1], 0.f);
            float v2 = fmaxf(acc[mt][ntl][2], 0.f);
            float v3 = fmaxf(acc[mt][ntl][3], 0.f);
            *(u2v*)(xz + eidx) = (u2v){pkbf(v0, v1), pkbf(v2, v3)};
        }

    __syncthreads();   // bar 2: z ready

    // ---- phase 3: out[64,30] = z @ W4; A-frags via ds_read_b64_tr_b16 ----
    unsigned base = (unsigned)(size_t)&xz[0] + (unsigned)(2 * mq) * 4096u
                  + (unsigned)(lane * 8);
    u2v f0[4][2], f1[4][2];
    #pragma unroll
    for (int c = 0; c < 4; ++c) {
        unsigned a0 = base + c * 1024;
        unsigned a1 = a0 + 4096;
        asm volatile("ds_read_b64_tr_b16 %0, %1" : "=v"(f0[c][0]) : "v"(a0));
        asm volatile("ds_read_b64_tr_b16 %0, %1 offset:512" : "=v"(f0[c][1]) : "v"(a0));
        asm volatile("ds_read_b64_tr_b16 %0, %1" : "=v"(f1[c][0]) : "v"(a1));
        asm volatile("ds_read_b64_tr_b16 %0, %1 offset:512" : "=v"(f1[c][1]) : "v"(a1));
    }
    asm volatile("s_waitcnt lgkmcnt(0)" ::: "memory");
    __builtin_amdgcn_sched_barrier(0);

    f4v oa0 = (f4v){b4i, b4i, b4i, b4i};
    f4v oa1 = oa0;
    #pragma unroll
    for (int kt = 0; kt < 4; ++kt) {
        s8v z0 = __builtin_bit_cast(s8v,
            (u4v){f0[kt][0][0], f0[kt][0][1], f0[kt][1][0], f0[kt][1][1]});
        s8v z1 = __builtin_bit_cast(s8v,
            (u4v){f1[kt][0][0], f1[kt][0][1], f1[kt][1][0], f1[kt][1][1]});
        oa0 = __builtin_amdgcn_mfma_f32_16x16x32_bf16(z0, wh[kt], oa0, 0, 0, 0);
        oa0 = __builtin_amdgcn_mfma_f32_16x16x32_bf16(z0, wl[kt], oa0, 0, 0, 0);
        oa1 = __builtin_amdgcn_mfma_f32_16x16x32_bf16(z1, wh[kt], oa1, 0, 0, 0);
        oa1 = __builtin_amdgcn_mfma_f32_16x16x32_bf16(z1, wl[kt], oa1, 0, 0, 0);
    }
    #pragma unroll
    for (int mi = 0; mi < 2; ++mi) {
        f4v oa = mi ? oa1 : oa0;
        #pragma unroll
        for (int i = 0; i < 4; ++i) {
            int grow = row0 + mq * 32 + mi * 16 + p * 4 + i;
            float v = oa[i];
            if (ocol < AD) {
                float tc = fminf(fmaxf(v, -20.f), 20.f);
                float e = __expf(2.f * tc);
                om[(size_t)grow * AD + ocol] = (e - 1.f) / (e + 1.f);
            } else if (ocol < 2 * AD) {
                os[(size_t)grow * AD + (ocol - AD)] = __expf(v);
            }
        }
    }
}

extern "C" void kernel_launch(void* const* d_in, const int* in_sizes, int n_in,
                              void* d_out, int out_size, void* d_ws, size_t ws_size,
                              hipStream_t stream) {
    const float* x    = (const float*)d_in[0];
    const float* sale = (const float*)d_in[1];
    const float* W1   = (const float*)d_in[2];
    const float* b1   = (const float*)d_in[3];
    const float* W2   = (const float*)d_in[4];
    const float* b2   = (const float*)d_in[5];
    const float* W3   = (const float*)d_in[6];
    const float* b3   = (const float*)d_in[7];
    const float* W4   = (const float*)d_in[8];
    const float* b4   = (const float*)d_in[9];

    int B = in_sizes[1];                       // sale_predictions is [B,1]
    float* om = (float*)d_out;                 // action_mean flat [B*15]
    float* os = om + (size_t)B * AD;           // action_std  flat [B*15]
    unsigned short* pk = (unsigned short*)d_ws;  // 25600 shorts = 51.2 KB

    pack_kernel<<<32, 256, 0, stream>>>(W3, W4, W1, W2, pk);
    actor_fused<<<B / 64, 256, 0, stream>>>(x, sale, b1, b2, b3, b4,
                                            pk, om, os);
}

// Round 23
// 44.335 us; speedup vs baseline: 1.1327x; 1.0114x over previous
//
#include <hip/hip_runtime.h>

// Actor MLP, B=262144 rows, fp32 in/out. All three GEMM stages on MFMA.
// R23 = R22 + LDS halved (24576 -> 16384) by aliasing s INTO x-slice0:
//  - gp-loop: p0 lane reads x slot gp (sole consumer of slice0 slots 0-6;
//    p1-3 read slice1, slot 7 consumed by hoisted k8 loads) then writes the
//    two s-pairs (g=2gp,2gp+1) back into the SAME 16B slot. Same-lane RAW,
//    lockstep-safe. Sale + K-pad (k=56..63) -> slot 7 b128 write after k8
//    hoist. Phase-2 ah addressing byte-identical, based at xz.
//  - z-staging overwrites s's home -> bar2 split: bar2a (s reads done) /
//    bar2b (z ready). 3 barriers total.
//  -> 16384 B LDS = 8 blocks/CU (32-wave cap) vs 6.
// Phases 2+3 otherwise unchanged (bf16 MFMA, B hi+lo, C/D z + tr_b16).

typedef float f4v  __attribute__((ext_vector_type(4)));
typedef short s8v  __attribute__((ext_vector_type(8)));
typedef _Float16 h8v __attribute__((ext_vector_type(8)));
typedef unsigned u2v __attribute__((ext_vector_type(2)));
typedef unsigned u4v __attribute__((ext_vector_type(4)));

constexpr int NG = 14, GI = 9, FH = 128, AD = 15;

__device__ __forceinline__ unsigned short f2bf(float f) {
    unsigned u = __builtin_bit_cast(unsigned, f);
    return (unsigned short)((u + 0x7fffu + ((u >> 16) & 1u)) >> 16);
}
__device__ __forceinline__ float bf2f(unsigned short h) {
    return __builtin_bit_cast(float, (unsigned)h << 16);
}
__device__ __forceinline__ f4v load4u(const float* p) {
    f4v v; __builtin_memcpy(&v, p, 16); return v;
}
__device__ __forceinline__ unsigned pkh(float a, float b) {
    return __builtin_bit_cast(unsigned, __builtin_amdgcn_cvt_pkrtz(a, b));
}
__device__ __forceinline__ unsigned pkbf(float a, float b) {
    unsigned r;
    asm("v_cvt_pk_bf16_f32 %0, %1, %2" : "=v"(r) : "v"(a), "v"(b));
    return r;
}

// pk layout (shorts): W3h[0,8192) W3l[8192,16384) W4h[16384,20480)
// W4l[20480,24576) W1T[24576,25088) W2T[25088,25600)
__global__ void pack_kernel(const float* __restrict__ W3,
                            const float* __restrict__ W4,
                            const float* __restrict__ W1,
                            const float* __restrict__ W2,
                            unsigned short* __restrict__ pk) {
    unsigned short* W3h = pk;
    unsigned short* W3l = pk + 8192;
    unsigned short* W4h = pk + 16384;
    unsigned short* W4l = pk + 20480;
    int t = blockIdx.x * 256 + threadIdx.x;
    if (t < 8192) {
        int j = t & 7, l = (t >> 3) & 63, nt = (t >> 9) & 7, kt = t >> 12;
        int k = kt * 32 + (l >> 4) * 8 + j, n = nt * 16 + (l & 15);
        float v = (k < 57) ? W3[k * FH + n] : 0.f;
        unsigned short h = f2bf(v);
        W3h[t] = h;
        W3l[t] = f2bf(v - bf2f(h));
    }
    if (t < 4096) {
        int j = t & 7, l = (t >> 3) & 63, nt = (t >> 9) & 1, kt = t >> 10;
        int k = kt * 32 + (l >> 4) * 8 + j, n = nt * 16 + (l & 15);
        float v = (n < 30) ? W4[k * 30 + n] : 0.f;
        unsigned short h = f2bf(v);
        W4h[t] = h;
        W4l[t] = f2bf(v - bf2f(h));
    }
    if (t < 512) {   // W1T/W2T A-frags
        int l = t >> 3, j = t & 7;
        int p = l >> 4, m = l & 15;
        // layer1: p0 j0-3 -> k=j; p0 j4 -> k=8; p1 j0-3 -> k=4+j; else 0.
        float v1 = 0.f;
        if (p == 0 && j < 4)       v1 = W1[j * 16 + m];
        else if (p == 0 && j == 4) v1 = W1[8 * 16 + m];
        else if (p == 1 && j < 4)  v1 = W1[(4 + j) * 16 + m];
        // layer2: kappa2(p,j) = 4p+j for j<4 (h-frag slot order), else 0.
        int k2 = (j < 4) ? (p * 4 + j) : 99;
        float v2 = (k2 < 16 && m < 4) ? W2[k2 * 4 + m] : 0.f;
        _Float16 h1 = (_Float16)v1, h2 = (_Float16)v2;
        pk[24576 + t] = __builtin_bit_cast(unsigned short, h1);
        pk[25088 + t] = __builtin_bit_cast(unsigned short, h2);
    }
}

__global__ __launch_bounds__(256, 4) void actor_fused(
    const float* __restrict__ x,     // [B,126]
    const float* __restrict__ sale,  // [B,1]
    const float* __restrict__ b1,    // [16]
    const float* __restrict__ b2,    // [4]
    const float* __restrict__ b3,    // [128]
    const float* __restrict__ b4,    // [30]
    const unsigned short* __restrict__ pk,
    float* __restrict__ om, float* __restrict__ os)
{
    // xz 16384 B, three lives:
    //  1. x fp16: slice0 [0,8192) k0-3 pairs + k8 g0-7 in slot7;
    //     slice1 [8192,16384) k4-7 pairs + k8 g8-13. 128B rows, XOR-swizzled.
    //  2. s bf16 (during phase 1): written in-place into slice0 (slots 0-6 =
    //     k0..55, slot 7 = sale + zero pad k56..63). Same row swizzle.
    //  3. z bf16 tiled (after bar2a): all 16384 B.
    __shared__ unsigned short xz[8192];

    const int tid  = threadIdx.x;
    const int wv   = __builtin_amdgcn_readfirstlane(tid >> 6);  // wave 0..3
    const int lane = tid & 63;
    const int row0 = blockIdx.x * 64;
    const int p    = lane >> 4;
    const int col  = lane & 15;
    char* xzb = (char*)xz;

    // ---- hoisted phase-1 A-frags + biases ----
    const h8v w1t = __builtin_bit_cast(h8v, *(const s8v*)(pk + 24576 + lane * 8));
    const h8v w2t = __builtin_bit_cast(h8v, *(const s8v*)(pk + 25088 + lane * 8));
    const f4v b1f = load4u(b1 + p * 4);
    const f4v b2f = load4u(b2);
    // ---- hoisted phase-2 weight B-frags + b3 (latency hides under phase 1) --
    const s8v* W3hv = (const s8v*)pk;
    const s8v* W3lv = (const s8v*)(pk + 8192);
    s8v bh[2][2], bl[2][2];
    #pragma unroll
    for (int kt = 0; kt < 2; ++kt)
        #pragma unroll
        for (int ntl = 0; ntl < 2; ++ntl) {
            int nt = 2 * wv + ntl;
            bh[kt][ntl] = W3hv[(kt * 8 + nt) * 64 + lane];
            bl[kt][ntl] = W3lv[(kt * 8 + nt) * 64 + lane];
        }
    const float bv0 = b3[32 * wv + col];
    const float bv1 = b3[32 * wv + 16 + col];

    // ---- wave-private x stage: 224 (row,g) units per wave ----
    {
        const float* xw0 = x + (size_t)(row0 + 16 * wv) * (NG * GI);
        #pragma unroll
        for (int i = 0; i < 4; ++i) {
            int unit = i * 64 + lane;
            if (i < 3 || lane < 32) {           // 224 units
                int rl = (unit * 149797) >> 21;  // unit / 14
                int g  = unit - rl * 14;
                const float* xs = xw0 + rl * 126 + g * 9;
                f4v a = load4u(xs);
                f4v b = load4u(xs + 4);
                float c = xs[8];
                int r  = 16 * wv + rl;
                int sw = (r & 7) << 4;
                int rb = r * 128;
                *(u2v*)(xzb + (rb + ((g * 8) ^ sw))) =
                    (u2v){pkh(a[0], a[1]), pkh(a[2], a[3])};
                *(u2v*)(xzb + 8192 + (rb + ((g * 8) ^ sw))) =
                    (u2v){pkh(b[0], b[1]), pkh(b[2], b[3])};
                _Float16 ch = (_Float16)c;
                int k8off = (g < 8 ? 0 : 8192) + rb + ((112 + (g & 7) * 2) ^ sw);
                *(unsigned short*)(xzb + k8off) =
                    __builtin_bit_cast(unsigned short, ch);
            }
        }
    }

    // ---- phase 1: virtual-row MFMA; wave wv owns rows 16wv..16wv+15 ----
    const int r1 = 16 * wv + col;
    const int ssw = (r1 & 7) << 4;
    const char* xrow = xzb + (p ? 8192 : 0) + r1 * 128;   // p>=2: garbage, A=0
    const float sv = sale[row0 + r1];
    // all 14 k8 values: slot 7 of both slices of row r1 (consumed here, then
    // slot 7 of slice0 is recycled for s k=56..63)
    const u4v k8A = *(const u4v*)(xzb + r1 * 128 + (112 ^ ssw));
    const u4v k8B = *(const u4v*)(xzb + 8192 + r1 * 128 + (112 ^ ssw));
    if (p == 0) {   // sale (k=56) + zero pad (k=57..63) into slice0 slot 7
        *(u4v*)(xzb + r1 * 128 + (112 ^ ssw)) =
            (u4v){(unsigned)f2bf(sv), 0u, 0u, 0u};
    }
    const int sbase = r1 * 128;

    #pragma unroll
    for (int gp = 0; gp < 7; ++gp) {
        u4v dv = *(const u4v*)(xrow + ((gp * 16) ^ ssw));   // ds_read_b128
        unsigned sq[4];   // two s-pairs for g=2gp, 2gp+1
        #pragma unroll
        for (int gi = 0; gi < 2; ++gi) {
            const int g = 2 * gp + gi;
            unsigned wk = (g < 8) ? k8A[g >> 1] : k8B[(g - 8) >> 1];
            unsigned k8v = (g & 1) ? (wk >> 16) : (wk & 0xffffu);
            h8v xb = __builtin_bit_cast(h8v,
                (u4v){dv[2 * gi], dv[2 * gi + 1], k8v, 0u});
            f4v ha = __builtin_amdgcn_mfma_f32_16x16x32_f16(w1t, xb, b1f, 0, 0, 0);
            float h0 = fmaxf(ha[0], 0.f), h1 = fmaxf(ha[1], 0.f);
            float h2 = fmaxf(ha[2], 0.f), h3 = fmaxf(ha[3], 0.f);
            h8v hb = __builtin_bit_cast(h8v,
                (u4v){pkh(h0, h1), pkh(h2, h3), 0u, 0u});
            f4v sa = __builtin_amdgcn_mfma_f32_16x16x32_f16(w2t, hb, b2f, 0, 0, 0);
            float s0 = fmaxf(sa[0], 0.f), s1 = fmaxf(sa[1], 0.f);
            float s2 = fmaxf(sa[2], 0.f), s3 = fmaxf(sa[3], 0.f);
            sq[2 * gi]     = pkbf(s0, s1);
            sq[2 * gi + 1] = pkbf(s2, s3);
        }
        // write s for g=2gp,2gp+1 back into slice0 slot gp (just read above;
        // p0 lane is this slot's only reader -> same-lane RAW, lockstep-safe)
        if (p == 0) {
            *(u4v*)(xzb + (sbase + ((gp * 16) ^ ssw))) =
                (u4v){sq[0], sq[1], sq[2], sq[3]};
        }
    }

    __syncthreads();   // bar 1: all s ready (s lives in slice0)

    // ---------------- phase 2: z[64,128] = s[64,64] @ W3  (MFMA) ----------
    f4v acc[4][2];
    #pragma unroll
    for (int mt = 0; mt < 4; ++mt) {
        acc[mt][0] = (f4v){bv0, bv0, bv0, bv0};
        acc[mt][1] = (f4v){bv1, bv1, bv1, bv1};
    }
    #pragma unroll
    for (int kt = 0; kt < 2; ++kt) {
        s8v ah[4];
        #pragma unroll
        for (int mt = 0; mt < 4; ++mt) {
            int rr = mt * 16 + col;
            int byt = (rr * 128 + kt * 64 + p * 16) ^ ((rr & 7) << 4);
            ah[mt] = *(const s8v*)(xzb + byt);
        }
        #pragma unroll
        for (int mt = 0; mt < 4; ++mt)
            #pragma unroll
            for (int ntl = 0; ntl < 2; ++ntl) {
                acc[mt][ntl] = __builtin_amdgcn_mfma_f32_16x16x32_bf16(ah[mt], bh[kt][ntl], acc[mt][ntl], 0, 0, 0);
                acc[mt][ntl] = __builtin_amdgcn_mfma_f32_16x16x32_bf16(ah[mt], bl[kt][ntl], acc[mt][ntl], 0, 0, 0);
            }
    }

    // ---- hoisted phase-3 weight B-frags + b4 (latency hides over bar2a) ----
    const s8v* W4hv = (const s8v*)(pk + 16384);
    const s8v* W4lv = (const s8v*)(pk + 20480);
    const int mq   = __builtin_amdgcn_readfirstlane(wv >> 1);  // row-half
    const int nq   = __builtin_amdgcn_readfirstlane(wv & 1);   // col-half
    const int ocol = nq * 16 + col;
    s8v wh[4], wl[4];
    #pragma unroll
    for (int kt = 0; kt < 4; ++kt) {
        wh[kt] = W4hv[(kt * 2 + nq) * 64 + lane];
        wl[kt] = W4lv[(kt * 2 + nq) * 64 + lane];
    }
    const float b4i = (ocol < 30) ? b4[ocol] : 0.f;

    __syncthreads();   // bar 2a: all s reads done; slice0 now reusable for z

    // stage relu(z) into C/D-native tiled layout (2 cvt_pk + b64 per frag)
    #pragma unroll
    for (int mt = 0; mt < 4; ++mt)
        #pragma unroll
        for (int ntl = 0; ntl < 2; ++ntl) {
            int kk  = ntl * 16 + col;               // K & 31 (chunk = wv)
            int tau = (kk & 4) ? 4 + (kk >> 3) : (kk >> 3);
            int eidx = mt * 2048 + wv * 512 + tau * 64 + (kk & 3) * 16 + (p << 2);
            float v0 = fmaxf(acc[mt][ntl][0], 0.f);
            float v1 = fmaxf(acc[mt][ntl][1], 0.f);
            float v2 = fmaxf(acc[mt][ntl][2], 0.f);
            float v3 = fmaxf(acc[mt][ntl][3], 0.f);
            *(u2v*)(xz + eidx) = (u2v){pkbf(v0, v1), pkbf(v2, v3)};
        }

    __syncthreads();   // bar 2b: z ready

    // ---- phase 3: out[64,30] = z @ W4; A-frags via ds_read_b64_tr_b16 ----
    unsigned base = (unsigned)(size_t)&xz[0] + (unsigned)(2 * mq) * 4096u
                  + (unsigned)(lane * 8);
    u2v f0[4][2], f1[4][2];
    #pragma unroll
    for (int c = 0; c < 4; ++c) {
        unsigned a0 = base + c * 1024;
        unsigned a1 = a0 + 4096;
        asm volatile("ds_read_b64_tr_b16 %0, %1" : "=v"(f0[c][0]) : "v"(a0));
        asm volatile("ds_read_b64_tr_b16 %0, %1 offset:512" : "=v"(f0[c][1]) : "v"(a0));
        asm volatile("ds_read_b64_tr_b16 %0, %1" : "=v"(f1[c][0]) : "v"(a1));
        asm volatile("ds_read_b64_tr_b16 %0, %1 offset:512" : "=v"(f1[c][1]) : "v"(a1));
    }
    asm volatile("s_waitcnt lgkmcnt(0)" ::: "memory");
    __builtin_amdgcn_sched_barrier(0);

    f4v oa0 = (f4v){b4i, b4i, b4i, b4i};
    f4v oa1 = oa0;
    #pragma unroll
    for (int kt = 0; kt < 4; ++kt) {
        s8v z0 = __builtin_bit_cast(s8v,
            (u4v){f0[kt][0][0], f0[kt][0][1], f0[kt][1][0], f0[kt][1][1]});
        s8v z1 = __builtin_bit_cast(s8v,
            (u4v){f1[kt][0][0], f1[kt][0][1], f1[kt][1][0], f1[kt][1][1]});
        oa0 = __builtin_amdgcn_mfma_f32_16x16x32_bf16(z0, wh[kt], oa0, 0, 0, 0);
        oa0 = __builtin_amdgcn_mfma_f32_16x16x32_bf16(z0, wl[kt], oa0, 0, 0, 0);
        oa1 = __builtin_amdgcn_mfma_f32_16x16x32_bf16(z1, wh[kt], oa1, 0, 0, 0);
        oa1 = __builtin_amdgcn_mfma_f32_16x16x32_bf16(z1, wl[kt], oa1, 0, 0, 0);
    }
    #pragma unroll
    for (int mi = 0; mi < 2; ++mi) {
        f4v oa = mi ? oa1 : oa0;
        #pragma unroll
        for (int i = 0; i < 4; ++i) {
            int grow = row0 + mq * 32 + mi * 16 + p * 4 + i;
            float v = oa[i];
            if (ocol < AD) {
                float tc = fminf(fmaxf(v, -20.f), 20.f);
                float e = __expf(2.f * tc);
                om[(size_t)grow * AD + ocol] = (e - 1.f) / (e + 1.f);
            } else if (ocol < 2 * AD) {
                os[(size_t)grow * AD + (ocol - AD)] = __expf(v);
            }
        }
    }
}

extern "C" void kernel_launch(void* const* d_in, const int* in_sizes, int n_in,
                              void* d_out, int out_size, void* d_ws, size_t ws_size,
                              hipStream_t stream) {
    const float* x    = (const float*)d_in[0];
    const float* sale = (const float*)d_in[1];
    const float* W1   = (const float*)d_in[2];
    const float* b1   = (const float*)d_in[3];
    const float* W2   = (const float*)d_in[4];
    const float* b2   = (const float*)d_in[5];
    const float* W3   = (const float*)d_in[6];
    const float* b3   = (const float*)d_in[7];
    const float* W4   = (const float*)d_in[8];
    const float* b4   = (const float*)d_in[9];

    int B = in_sizes[1];                       // sale_predictions is [B,1]
    float* om = (float*)d_out;                 // action_mean flat [B*15]
    float* os = om + (size_t)B * AD;           // action_std  flat [B*15]
    unsigned short* pk = (unsigned short*)d_ws;  // 25600 shorts = 51.2 KB

    pack_kernel<<<32, 256, 0, stream>>>(W3, W4, W1, W2, pk);
    actor_fused<<<B / 64, 256, 0, stream>>>(x, sale, b1, b2, b3, b4,
                                            pk, om, os);
}